// Round 1
// baseline (1959.896 us; speedup 1.0000x reference)
//
#include <hip/hip_runtime.h>
#include <float.h>

#define NB 16
#define N1 16384
#define NP1 512
#define NS1 32
#define N2 512
#define NP2 128
#define NS2 64
#define TILE1 2048

// ---------- numpy-exact float helpers (no FMA contraction) ----------
__device__ __forceinline__ float sq3_np(float x, float y, float z) {
#pragma clang fp contract(off)
  return ((x * x) + (y * y)) + (z * z);
}
__device__ __forceinline__ float dot3_np(float ax, float ay, float az,
                                         float bx, float by, float bz) {
#pragma clang fp contract(off)
  return ((ax * bx) + (ay * by)) + (az * bz);
}
__device__ __forceinline__ float sqr_np(float ca, float sb, float dot) {
#pragma clang fp contract(off)
  return (ca + sb) - (2.0f * dot);
}
__device__ __forceinline__ float distmin_np(float px, float py, float pz,
                                            float cx, float cy, float cz,
                                            float old) {
#pragma clang fp contract(off)
  float dx = px - cx, dy = py - cy, dz = pz - cz;
  float d = ((dx * dx) + (dy * dy)) + (dz * dz);
  return d < old ? d : old;
}

// ---------- workspace layout (float-unit offsets) ----------
constexpr size_t OFF_W1T1 = 0;        // 3x64   -> 192 (pad to 256)
constexpr size_t OFF_W2T1 = 256;      // 64x64  -> 4096
constexpr size_t OFF_W3T1 = 4352;     // 64x128 -> 8192
constexpr size_t OFF_W1T2 = 12544;    // 131x128-> 16768
constexpr size_t OFF_W2T2 = 29312;    // 128x256-> 32768
constexpr size_t OFF_W3T2 = 62080;    // 256x256-> 65536
constexpr size_t OFF_NORM1 = 127616;  // 16x16384
constexpr size_t OFF_L1XYZ = 389760;  // 16x512x3
constexpr size_t OFF_NORM2 = 414336;  // 16x512
constexpr size_t OFF_L1PTS = 422528;  // 16x512x128
constexpr size_t OFF_FPS1I = 1471104; // 16x512 ints
constexpr size_t OFF_FPS2I = 1479296; // 16x128 ints
constexpr size_t WS_FLOATS = 1481344;

// ---------- prep: point norms + weight transposes ----------
__global__ void prep_kernel(const float* __restrict__ xyz,
                            const float* __restrict__ w1a, const float* __restrict__ w2a,
                            const float* __restrict__ w3a, const float* __restrict__ w1b,
                            const float* __restrict__ w2b, const float* __restrict__ w3b,
                            float* __restrict__ ws) {
  int tid = blockIdx.x * blockDim.x + threadIdx.x;
  int stride = gridDim.x * blockDim.x;
  const int nNorm = NB * N1;
  const int e1 = nNorm + 192;
  const int e2 = e1 + 64 * 64;
  const int e3 = e2 + 128 * 64;
  const int e4 = e3 + 128 * 131;
  const int e5 = e4 + 256 * 128;
  const int e6 = e5 + 256 * 256;
  for (int i = tid; i < e6; i += stride) {
    if (i < nNorm) {
      ws[OFF_NORM1 + i] =
          sq3_np(xyz[(size_t)i * 3], xyz[(size_t)i * 3 + 1], xyz[(size_t)i * 3 + 2]);
    } else if (i < e1) {
      int j = i - nNorm; int o = j & 63, c = j >> 6;   // c<3
      ws[OFF_W1T1 + j] = w1a[o * 3 + c];
    } else if (i < e2) {
      int j = i - e1; int o = j & 63, c = j >> 6;
      ws[OFF_W2T1 + j] = w2a[o * 64 + c];
    } else if (i < e3) {
      int j = i - e2; int o = j & 127, c = j >> 7;
      ws[OFF_W3T1 + j] = w3a[o * 64 + c];
    } else if (i < e4) {
      int j = i - e3; int o = j & 127, c = j >> 7;     // c<131
      ws[OFF_W1T2 + j] = w1b[o * 131 + c];
    } else if (i < e5) {
      int j = i - e4; int o = j & 255, c = j >> 8;
      ws[OFF_W2T2 + j] = w2b[o * 128 + c];
    } else {
      int j = i - e5; int o = j & 255, c = j >> 8;
      ws[OFF_W3T2 + j] = w3b[o * 256 + c];
    }
  }
}

// ---------- FPS over N1=16384, npoint=512 : 16 blocks x 1024 threads ----------
__global__ __launch_bounds__(1024) void fps1_kernel(const float* __restrict__ xyz,
                                                    int* __restrict__ out_idx) {
  int b = blockIdx.x;
  int t = threadIdx.x;
  int w = t >> 6, lane = t & 63;
  const float* xb = xyz + (size_t)b * N1 * 3;
  float px[16], py[16], pz[16], dist[16];
#pragma unroll
  for (int k = 0; k < 16; ++k) {
    int p = k * 1024 + t;
    px[k] = xb[p * 3];
    py[k] = xb[p * 3 + 1];
    pz[k] = xb[p * 3 + 2];
    dist[k] = 1e10f;
  }
  __shared__ float s_v[16], s_x[16], s_y[16], s_z[16];
  __shared__ int s_i[16];
  if (t == 0) out_idx[b * NP1] = 0;
  float cx = xb[0], cy = xb[1], cz = xb[2];
  for (int s = 1; s < NP1; ++s) {
    float bv = -1.0f; int bi = 0;
    float wx = 0.f, wy = 0.f, wz = 0.f;
#pragma unroll
    for (int k = 0; k < 16; ++k) {
      float nd = distmin_np(px[k], py[k], pz[k], cx, cy, cz, dist[k]);
      dist[k] = nd;
      if (nd > bv) { bv = nd; bi = k * 1024 + t; wx = px[k]; wy = py[k]; wz = pz[k]; }
    }
#pragma unroll
    for (int off = 1; off < 64; off <<= 1) {
      float ov = __shfl_xor(bv, off);
      int oi = __shfl_xor(bi, off);
      float ox = __shfl_xor(wx, off), oy = __shfl_xor(wy, off), oz = __shfl_xor(wz, off);
      if (ov > bv || (ov == bv && oi < bi)) { bv = ov; bi = oi; wx = ox; wy = oy; wz = oz; }
    }
    if (lane == 0) { s_v[w] = bv; s_i[w] = bi; s_x[w] = wx; s_y[w] = wy; s_z[w] = wz; }
    __syncthreads();
    float fv = s_v[0]; int fi = s_i[0];
    float fx = s_x[0], fy = s_y[0], fz = s_z[0];
#pragma unroll
    for (int i = 1; i < 16; ++i) {
      float v2 = s_v[i]; int i2 = s_i[i];
      if (v2 > fv || (v2 == fv && i2 < fi)) { fv = v2; fi = i2; fx = s_x[i]; fy = s_y[i]; fz = s_z[i]; }
    }
    cx = fx; cy = fy; cz = fz;
    if (t == 0) out_idx[b * NP1 + s] = fi;
    __syncthreads();
  }
}

// ---------- FPS over N2=512, npoint=128 : 16 blocks x 64 threads (1 wave) ----------
__global__ __launch_bounds__(64) void fps2_kernel(const float* __restrict__ l1_xyz,
                                                  int* __restrict__ out_idx) {
  int b = blockIdx.x;
  int lane = threadIdx.x;
  const float* xb = l1_xyz + (size_t)b * N2 * 3;
  float px[8], py[8], pz[8], dist[8];
#pragma unroll
  for (int k = 0; k < 8; ++k) {
    int p = k * 64 + lane;
    px[k] = xb[p * 3]; py[k] = xb[p * 3 + 1]; pz[k] = xb[p * 3 + 2];
    dist[k] = 1e10f;
  }
  if (lane == 0) out_idx[b * NP2] = 0;
  float cx = xb[0], cy = xb[1], cz = xb[2];
  for (int s = 1; s < NP2; ++s) {
    float bv = -1.0f; int bi = 0;
    float wx = 0.f, wy = 0.f, wz = 0.f;
#pragma unroll
    for (int k = 0; k < 8; ++k) {
      float nd = distmin_np(px[k], py[k], pz[k], cx, cy, cz, dist[k]);
      dist[k] = nd;
      if (nd > bv) { bv = nd; bi = k * 64 + lane; wx = px[k]; wy = py[k]; wz = pz[k]; }
    }
#pragma unroll
    for (int off = 1; off < 64; off <<= 1) {
      float ov = __shfl_xor(bv, off);
      int oi = __shfl_xor(bi, off);
      float ox = __shfl_xor(wx, off), oy = __shfl_xor(wy, off), oz = __shfl_xor(wz, off);
      if (ov > bv || (ov == bv && oi < bi)) { bv = ov; bi = oi; wx = ox; wy = oy; wz = oz; }
    }
    cx = wx; cy = wy; cz = wz;
    if (lane == 0) out_idx[b * NP2 + s] = bi;
  }
}

// ---------- SA1 fused: ball query (first-32 ascending) + MLP(3->64->64->128) + max ----------
// 2048 blocks x 256 threads; wave w handles centroid s = (blockIdx&127)*4 + w of batch blockIdx>>7
__global__ __launch_bounds__(256) void sa1_kernel(
    const float* __restrict__ xyz, const float* __restrict__ norms1,
    const int* __restrict__ fps1_idx,
    const float* __restrict__ w1T, const float* __restrict__ bias1,
    const float* __restrict__ w2T, const float* __restrict__ bias2,
    const float* __restrict__ w3T, const float* __restrict__ bias3,
    float* __restrict__ l1_xyz, float* __restrict__ norms2, float* __restrict__ l1_pts) {
  __shared__ float4 tile[TILE1];
  __shared__ float blx[4 * NS1], bly[4 * NS1], blz[4 * NS1];
  int b = blockIdx.x >> 7;
  int t = threadIdx.x;
  int w = t >> 6, lane = t & 63;
  int s = ((blockIdx.x & 127) << 2) + w;
  const float* xb = xyz + (size_t)b * N1 * 3;
  const float* nb = norms1 + (size_t)b * N1;
  int cidx = fps1_idx[b * NP1 + s];
  float cx = xb[cidx * 3], cy = xb[cidx * 3 + 1], cz = xb[cidx * 3 + 2];
  float ca = nb[cidx];
  const float r2 = (float)(0.04 * 0.04);
  int tot = 0;
  for (int t0 = 0; t0 < N1; t0 += TILE1) {
    for (int i = t; i < TILE1; i += 256) {
      int p = t0 + i;
      tile[i] = make_float4(xb[p * 3], xb[p * 3 + 1], xb[p * 3 + 2], nb[p]);
    }
    __syncthreads();
    for (int j = 0; j < TILE1; j += 256) {
      float4 p0 = tile[j + lane];
      float4 p1 = tile[j + 64 + lane];
      float4 p2 = tile[j + 128 + lane];
      float4 p3 = tile[j + 192 + lane];
      bool in0 = !(sqr_np(ca, p0.w, dot3_np(cx, cy, cz, p0.x, p0.y, p0.z)) > r2);
      bool in1 = !(sqr_np(ca, p1.w, dot3_np(cx, cy, cz, p1.x, p1.y, p1.z)) > r2);
      bool in2 = !(sqr_np(ca, p2.w, dot3_np(cx, cy, cz, p2.x, p2.y, p2.z)) > r2);
      bool in3 = !(sqr_np(ca, p3.w, dot3_np(cx, cy, cz, p3.x, p3.y, p3.z)) > r2);
      unsigned long long any = __ballot(in0 | in1 | in2 | in3);
      if (any) {  // rare slow path: append in ascending index order (q major, lane minor)
#define SA1_APPEND(inq, pq)                                                     \
        {                                                                       \
          unsigned long long m = __ballot(inq);                                 \
          if (m) {                                                              \
            int rank = __popcll(m & ((1ull << lane) - 1ull));                   \
            int slot = tot + rank;                                              \
            if (inq && slot < NS1) {                                            \
              blx[w * NS1 + slot] = pq.x - cx;                                  \
              bly[w * NS1 + slot] = pq.y - cy;                                  \
              blz[w * NS1 + slot] = pq.z - cz;                                  \
            }                                                                   \
            tot += (int)__popcll(m);                                            \
            if (tot > NS1) tot = NS1;                                           \
          }                                                                     \
        }
        SA1_APPEND(in0, p0)
        SA1_APPEND(in1, p1)
        SA1_APPEND(in2, p2)
        SA1_APPEND(in3, p3)
#undef SA1_APPEND
      }
    }
    __syncthreads();
  }
  // MLP over unique in-ball samples (duplicate padding is idempotent under max)
  int cnt = tot > 0 ? tot : 1;  // centroid is always in its own ball
  float m0 = -FLT_MAX, m1 = -FLT_MAX;
  for (int k = 0; k < cnt; ++k) {
    float fx = blx[w * NS1 + k], fy = bly[w * NS1 + k], fz = blz[w * NS1 + k];
    float h1 = bias1[lane] + w1T[lane] * fx + w1T[64 + lane] * fy + w1T[128 + lane] * fz;
    h1 = fmaxf(h1, 0.0f);
    float a = bias2[lane];
#pragma unroll 8
    for (int c = 0; c < 64; ++c) a += w2T[c * 64 + lane] * __shfl(h1, c);
    a = fmaxf(a, 0.0f);
    float a0 = bias3[lane], a1 = bias3[64 + lane];
#pragma unroll 8
    for (int c = 0; c < 64; ++c) {
      float hv = __shfl(a, c);
      a0 += w3T[c * 128 + lane] * hv;
      a1 += w3T[c * 128 + 64 + lane] * hv;
    }
    a0 = fmaxf(a0, 0.0f); a1 = fmaxf(a1, 0.0f);
    m0 = fmaxf(m0, a0); m1 = fmaxf(m1, a1);
  }
  float* op = l1_pts + ((size_t)b * NP1 + s) * 128;
  op[lane] = m0;
  op[64 + lane] = m1;
  if (lane == 0) {
    float* xp = l1_xyz + ((size_t)b * NP1 + s) * 3;
    xp[0] = cx; xp[1] = cy; xp[2] = cz;
    norms2[b * NP1 + s] = ca;
  }
}

// ---------- SA2 fused: ball query (first-64) + MLP(131->128->256->256) + max ----------
// 512 blocks x 256 threads; wave w -> centroid s = (blockIdx&31)*4 + w of batch blockIdx>>5
__global__ __launch_bounds__(256) void sa2_kernel(
    const float* __restrict__ l1_xyz, const float* __restrict__ norms2,
    const float* __restrict__ l1_pts, const int* __restrict__ fps2_idx,
    const float* __restrict__ w1T, const float* __restrict__ bias1,
    const float* __restrict__ w2T, const float* __restrict__ bias2,
    const float* __restrict__ w3T, const float* __restrict__ bias3,
    float* __restrict__ out) {
  __shared__ float sx[N2], sy[N2], sz[N2], sn[N2];
  __shared__ float blx[4 * NS2], bly[4 * NS2], blz[4 * NS2];
  __shared__ int bli[4 * NS2];
  int b = blockIdx.x >> 5;
  int t = threadIdx.x;
  int w = t >> 6, lane = t & 63;
  int s = ((blockIdx.x & 31) << 2) + w;
  const float* xb = l1_xyz + (size_t)b * N2 * 3;
  const float* nb = norms2 + (size_t)b * N2;
  for (int i = t; i < N2; i += 256) {
    sx[i] = xb[i * 3]; sy[i] = xb[i * 3 + 1]; sz[i] = xb[i * 3 + 2]; sn[i] = nb[i];
  }
  __syncthreads();
  int cidx = fps2_idx[b * NP2 + s];
  float cx = sx[cidx], cy = sy[cidx], cz = sz[cidx], ca = sn[cidx];
  const float r2 = (float)(0.08 * 0.08);
  int tot = 0;
  for (int j = 0; j < N2; j += 64) {
    int i = j + lane;
    float px = sx[i], py = sy[i], pz = sz[i], sb = sn[i];
    bool in = !(sqr_np(ca, sb, dot3_np(cx, cy, cz, px, py, pz)) > r2);
    unsigned long long m = __ballot(in);
    int rank = __popcll(m & ((1ull << lane) - 1ull));
    int slot = tot + rank;
    if (in && slot < NS2) {
      blx[w * NS2 + slot] = px - cx;
      bly[w * NS2 + slot] = py - cy;
      blz[w * NS2 + slot] = pz - cz;
      bli[w * NS2 + slot] = i;
    }
    tot += (int)__popcll(m);
    if (tot > NS2) tot = NS2;
  }
  __syncthreads();
  int cnt = tot > 0 ? tot : 1;
  float mx0 = -FLT_MAX, mx1 = -FLT_MAX, mx2 = -FLT_MAX, mx3 = -FLT_MAX;
  for (int k = 0; k < cnt; ++k) {
    float fx = blx[w * NS2 + k], fy = bly[w * NS2 + k], fz = blz[w * NS2 + k];
    int pidx = bli[w * NS2 + k];
    const float* fp = l1_pts + ((size_t)b * N2 + pidx) * 128;
    float a0 = bias1[lane] + w1T[lane] * fx + w1T[128 + lane] * fy + w1T[256 + lane] * fz;
    float a1 = bias1[64 + lane] + w1T[64 + lane] * fx + w1T[192 + lane] * fy + w1T[320 + lane] * fz;
#pragma unroll 4
    for (int c = 0; c < 128; ++c) {
      float fv = fp[c];
      a0 += w1T[(size_t)(3 + c) * 128 + lane] * fv;
      a1 += w1T[(size_t)(3 + c) * 128 + 64 + lane] * fv;
    }
    float h1a = fmaxf(a0, 0.0f), h1b = fmaxf(a1, 0.0f);
    float acc0 = bias2[lane], acc1 = bias2[64 + lane], acc2 = bias2[128 + lane], acc3 = bias2[192 + lane];
#pragma unroll 4
    for (int c = 0; c < 64; ++c) {
      float hv = __shfl(h1a, c);
      acc0 += w2T[(size_t)c * 256 + lane] * hv;
      acc1 += w2T[(size_t)c * 256 + 64 + lane] * hv;
      acc2 += w2T[(size_t)c * 256 + 128 + lane] * hv;
      acc3 += w2T[(size_t)c * 256 + 192 + lane] * hv;
    }
#pragma unroll 4
    for (int c = 0; c < 64; ++c) {
      float hv = __shfl(h1b, c);
      acc0 += w2T[(size_t)(64 + c) * 256 + lane] * hv;
      acc1 += w2T[(size_t)(64 + c) * 256 + 64 + lane] * hv;
      acc2 += w2T[(size_t)(64 + c) * 256 + 128 + lane] * hv;
      acc3 += w2T[(size_t)(64 + c) * 256 + 192 + lane] * hv;
    }
    float h20 = fmaxf(acc0, 0.0f), h21 = fmaxf(acc1, 0.0f);
    float h22 = fmaxf(acc2, 0.0f), h23 = fmaxf(acc3, 0.0f);
    float o0 = bias3[lane], o1 = bias3[64 + lane], o2 = bias3[128 + lane], o3 = bias3[192 + lane];
#define SA2_L3(hreg, rbase)                                                     \
    {                                                                           \
      _Pragma("unroll 4")                                                       \
      for (int c = 0; c < 64; ++c) {                                            \
        float hv = __shfl(hreg, c);                                             \
        o0 += w3T[(size_t)(rbase + c) * 256 + lane] * hv;                       \
        o1 += w3T[(size_t)(rbase + c) * 256 + 64 + lane] * hv;                  \
        o2 += w3T[(size_t)(rbase + c) * 256 + 128 + lane] * hv;                 \
        o3 += w3T[(size_t)(rbase + c) * 256 + 192 + lane] * hv;                 \
      }                                                                         \
    }
    SA2_L3(h20, 0)
    SA2_L3(h21, 64)
    SA2_L3(h22, 128)
    SA2_L3(h23, 192)
#undef SA2_L3
    mx0 = fmaxf(mx0, fmaxf(o0, 0.0f));
    mx1 = fmaxf(mx1, fmaxf(o1, 0.0f));
    mx2 = fmaxf(mx2, fmaxf(o2, 0.0f));
    mx3 = fmaxf(mx3, fmaxf(o3, 0.0f));
  }
  float* op = out + ((size_t)b * NP2 + s) * 256;
  op[lane] = mx0;
  op[64 + lane] = mx1;
  op[128 + lane] = mx2;
  op[192 + lane] = mx3;
}

extern "C" void kernel_launch(void* const* d_in, const int* in_sizes, int n_in,
                              void* d_out, int out_size, void* d_ws, size_t ws_size,
                              hipStream_t stream) {
  const float* xyz = (const float*)d_in[0];
  const float* sa1_w1 = (const float*)d_in[1];
  const float* sa1_b1 = (const float*)d_in[2];
  const float* sa1_w2 = (const float*)d_in[3];
  const float* sa1_b2 = (const float*)d_in[4];
  const float* sa1_w3 = (const float*)d_in[5];
  const float* sa1_b3 = (const float*)d_in[6];
  const float* sa2_w1 = (const float*)d_in[7];
  const float* sa2_b1 = (const float*)d_in[8];
  const float* sa2_w2 = (const float*)d_in[9];
  const float* sa2_b2 = (const float*)d_in[10];
  const float* sa2_w3 = (const float*)d_in[11];
  const float* sa2_b3 = (const float*)d_in[12];

  if (ws_size < WS_FLOATS * sizeof(float)) return;  // scratch too small: fail loudly

  float* ws = (float*)d_ws;
  float* w1T1 = ws + OFF_W1T1;
  float* w2T1 = ws + OFF_W2T1;
  float* w3T1 = ws + OFF_W3T1;
  float* w1T2 = ws + OFF_W1T2;
  float* w2T2 = ws + OFF_W2T2;
  float* w3T2 = ws + OFF_W3T2;
  float* norms1 = ws + OFF_NORM1;
  float* l1xyz = ws + OFF_L1XYZ;
  float* norms2 = ws + OFF_NORM2;
  float* l1pts = ws + OFF_L1PTS;
  int* fps1i = (int*)(ws + OFF_FPS1I);
  int* fps2i = (int*)(ws + OFF_FPS2I);

  prep_kernel<<<1024, 256, 0, stream>>>(xyz, sa1_w1, sa1_w2, sa1_w3, sa2_w1, sa2_w2, sa2_w3, ws);
  fps1_kernel<<<NB, 1024, 0, stream>>>(xyz, fps1i);
  sa1_kernel<<<NB * (NP1 / 4), 256, 0, stream>>>(xyz, norms1, fps1i, w1T1, sa1_b1, w2T1,
                                                 sa1_b2, w3T1, sa1_b3, l1xyz, norms2, l1pts);
  fps2_kernel<<<NB, 64, 0, stream>>>(l1xyz, fps2i);
  sa2_kernel<<<NB * (NP2 / 4), 256, 0, stream>>>(l1xyz, norms2, l1pts, fps2i, w1T2, sa2_b1,
                                                 w2T2, sa2_b2, w3T2, sa2_b3, (float*)d_out);
}

// Round 2
// 1104.280 us; speedup vs baseline: 1.7748x; 1.7748x over previous
//
#include <hip/hip_runtime.h>
#include <float.h>

#define NB 16
#define N1 16384
#define NP1 512
#define NS1 32
#define N2 512
#define NP2 128
#define NS2 64
#define TILE1 2048

// ---------- numpy-exact float helpers (no FMA contraction) ----------
__device__ __forceinline__ float sq3_np(float x, float y, float z) {
#pragma clang fp contract(off)
  return ((x * x) + (y * y)) + (z * z);
}
__device__ __forceinline__ float dot3_np(float ax, float ay, float az,
                                         float bx, float by, float bz) {
#pragma clang fp contract(off)
  return ((ax * bx) + (ay * by)) + (az * bz);
}
__device__ __forceinline__ float sqr_np(float ca, float sb, float dot) {
#pragma clang fp contract(off)
  return (ca + sb) - (2.0f * dot);
}
__device__ __forceinline__ float distmin_np(float px, float py, float pz,
                                            float cx, float cy, float cz,
                                            float old) {
#pragma clang fp contract(off)
  float dx = px - cx, dy = py - cy, dz = pz - cz;
  float d = ((dx * dx) + (dy * dy)) + (dz * dz);
  return d < old ? d : old;
}

// ---------- workspace layout (float-unit offsets) ----------
constexpr size_t OFF_W1T1 = 0;        // 3x64   -> 192 (pad to 256)
constexpr size_t OFF_W2T1 = 256;      // 64x64  -> 4096
constexpr size_t OFF_W3T1 = 4352;     // 64x128 -> 8192
constexpr size_t OFF_W1T2 = 12544;    // 131x128-> 16768
constexpr size_t OFF_W2T2 = 29312;    // 128x256-> 32768
constexpr size_t OFF_W3T2 = 62080;    // 256x256-> 65536
constexpr size_t OFF_NORM1 = 127616;  // 16x16384
constexpr size_t OFF_L1XYZ = 389760;  // 16x512x3
constexpr size_t OFF_NORM2 = 414336;  // 16x512
constexpr size_t OFF_L1PTS = 422528;  // 16x512x128
constexpr size_t OFF_FPS1I = 1471104; // 16x512 ints
constexpr size_t OFF_FPS2I = 1479296; // 16x128 ints
constexpr size_t WS_FLOATS = 1481344;

// ---------- prep: point norms + weight transposes ----------
__global__ void prep_kernel(const float* __restrict__ xyz,
                            const float* __restrict__ w1a, const float* __restrict__ w2a,
                            const float* __restrict__ w3a, const float* __restrict__ w1b,
                            const float* __restrict__ w2b, const float* __restrict__ w3b,
                            float* __restrict__ ws) {
  int tid = blockIdx.x * blockDim.x + threadIdx.x;
  int stride = gridDim.x * blockDim.x;
  const int nNorm = NB * N1;
  const int e1 = nNorm + 192;
  const int e2 = e1 + 64 * 64;
  const int e3 = e2 + 128 * 64;
  const int e4 = e3 + 128 * 131;
  const int e5 = e4 + 256 * 128;
  const int e6 = e5 + 256 * 256;
  for (int i = tid; i < e6; i += stride) {
    if (i < nNorm) {
      ws[OFF_NORM1 + i] =
          sq3_np(xyz[(size_t)i * 3], xyz[(size_t)i * 3 + 1], xyz[(size_t)i * 3 + 2]);
    } else if (i < e1) {
      int j = i - nNorm; int o = j & 63, c = j >> 6;   // c<3
      ws[OFF_W1T1 + j] = w1a[o * 3 + c];
    } else if (i < e2) {
      int j = i - e1; int o = j & 63, c = j >> 6;
      ws[OFF_W2T1 + j] = w2a[o * 64 + c];
    } else if (i < e3) {
      int j = i - e2; int o = j & 127, c = j >> 7;
      ws[OFF_W3T1 + j] = w3a[o * 64 + c];
    } else if (i < e4) {
      int j = i - e3; int o = j & 127, c = j >> 7;     // c<131
      ws[OFF_W1T2 + j] = w1b[o * 131 + c];
    } else if (i < e5) {
      int j = i - e4; int o = j & 255, c = j >> 8;
      ws[OFF_W2T2 + j] = w2b[o * 128 + c];
    } else {
      int j = i - e5; int o = j & 255, c = j >> 8;
      ws[OFF_W3T2 + j] = w3b[o * 256 + c];
    }
  }
}

// ---------- FPS over N1=16384, npoint=512 ----------
// 16 blocks x 512 threads, 32 pts/thread, all coords REGISTER-RESIDENT
// (__launch_bounds__(512,2) -> 256-VGPR budget; round-1 version was capped
//  at 64 VGPR and re-streamed 196KB/step from L2 -> 1730us).
// Argmax reduce: packed u64 key = (dist_bits<<32) | ~global_idx  -> max
// gives max-dist with first-occurrence (min idx) tie-break, 1 value to shuffle.
__global__ __launch_bounds__(512, 2) void fps1_kernel(const float* __restrict__ xyz,
                                                      int* __restrict__ out_idx) {
  int b = blockIdx.x;
  int t = threadIdx.x;
  int w = t >> 6, lane = t & 63;
  const float* xb = xyz + (size_t)b * N1 * 3;
  float px[32], py[32], pz[32], dist[32];
#pragma unroll
  for (int k = 0; k < 32; ++k) {
    int p = k * 512 + t;
    px[k] = xb[p * 3];
    py[k] = xb[p * 3 + 1];
    pz[k] = xb[p * 3 + 2];
    dist[k] = 1e10f;
  }
  __shared__ unsigned long long s_key[2][8];
  if (t == 0) out_idx[b * NP1] = 0;
  float cx = xb[0], cy = xb[1], cz = xb[2];
  for (int s = 1; s < NP1; ++s) {
    float bv = -1.0f; int bk = 0;
#pragma unroll
    for (int k = 0; k < 32; ++k) {
      float nd = distmin_np(px[k], py[k], pz[k], cx, cy, cz, dist[k]);
      dist[k] = nd;
      if (nd > bv) { bv = nd; bk = k; }  // strict > keeps smallest k on tie
    }
    unsigned int gidx = ((unsigned int)bk << 9) | (unsigned int)t;
    unsigned long long key =
        ((unsigned long long)__float_as_uint(bv) << 32) | (unsigned int)~gidx;
#pragma unroll
    for (int off = 1; off < 64; off <<= 1) {
      unsigned long long ok = __shfl_xor(key, off);
      if (ok > key) key = ok;
    }
    if (lane == 0) s_key[s & 1][w] = key;
    __syncthreads();  // one barrier/step; parity double-buffer avoids WAR
    unsigned long long fk = s_key[s & 1][0];
#pragma unroll
    for (int i = 1; i < 8; ++i) {
      unsigned long long k2 = s_key[s & 1][i];
      if (k2 > fk) fk = k2;
    }
    unsigned int fi = ~(unsigned int)fk;
    cx = xb[fi * 3]; cy = xb[fi * 3 + 1]; cz = xb[fi * 3 + 2];
    if (t == 0) out_idx[b * NP1 + s] = (int)fi;
  }
}

// ---------- FPS over N2=512, npoint=128 : 16 blocks x 64 threads (1 wave) ----------
__global__ __launch_bounds__(64) void fps2_kernel(const float* __restrict__ l1_xyz,
                                                  int* __restrict__ out_idx) {
  int b = blockIdx.x;
  int lane = threadIdx.x;
  const float* xb = l1_xyz + (size_t)b * N2 * 3;
  float px[8], py[8], pz[8], dist[8];
#pragma unroll
  for (int k = 0; k < 8; ++k) {
    int p = k * 64 + lane;
    px[k] = xb[p * 3]; py[k] = xb[p * 3 + 1]; pz[k] = xb[p * 3 + 2];
    dist[k] = 1e10f;
  }
  if (lane == 0) out_idx[b * NP2] = 0;
  float cx = xb[0], cy = xb[1], cz = xb[2];
  for (int s = 1; s < NP2; ++s) {
    float bv = -1.0f; int bi = 0;
    float wx = 0.f, wy = 0.f, wz = 0.f;
#pragma unroll
    for (int k = 0; k < 8; ++k) {
      float nd = distmin_np(px[k], py[k], pz[k], cx, cy, cz, dist[k]);
      dist[k] = nd;
      if (nd > bv) { bv = nd; bi = k * 64 + lane; wx = px[k]; wy = py[k]; wz = pz[k]; }
    }
#pragma unroll
    for (int off = 1; off < 64; off <<= 1) {
      float ov = __shfl_xor(bv, off);
      int oi = __shfl_xor(bi, off);
      float ox = __shfl_xor(wx, off), oy = __shfl_xor(wy, off), oz = __shfl_xor(wz, off);
      if (ov > bv || (ov == bv && oi < bi)) { bv = ov; bi = oi; wx = ox; wy = oy; wz = oz; }
    }
    cx = wx; cy = wy; cz = wz;
    if (lane == 0) out_idx[b * NP2 + s] = bi;
  }
}

// ---------- SA1 fused: ball query (first-32 ascending) + MLP(3->64->64->128) + max ----------
// 2048 blocks x 256 threads; wave w handles centroid s = (blockIdx&127)*4 + w of batch blockIdx>>7
__global__ __launch_bounds__(256) void sa1_kernel(
    const float* __restrict__ xyz, const float* __restrict__ norms1,
    const int* __restrict__ fps1_idx,
    const float* __restrict__ w1T, const float* __restrict__ bias1,
    const float* __restrict__ w2T, const float* __restrict__ bias2,
    const float* __restrict__ w3T, const float* __restrict__ bias3,
    float* __restrict__ l1_xyz, float* __restrict__ norms2, float* __restrict__ l1_pts) {
  __shared__ float4 tile[TILE1];
  __shared__ float blx[4 * NS1], bly[4 * NS1], blz[4 * NS1];
  int b = blockIdx.x >> 7;
  int t = threadIdx.x;
  int w = t >> 6, lane = t & 63;
  int s = ((blockIdx.x & 127) << 2) + w;
  const float* xb = xyz + (size_t)b * N1 * 3;
  const float* nb = norms1 + (size_t)b * N1;
  int cidx = fps1_idx[b * NP1 + s];
  float cx = xb[cidx * 3], cy = xb[cidx * 3 + 1], cz = xb[cidx * 3 + 2];
  float ca = nb[cidx];
  const float r2 = (float)(0.04 * 0.04);
  int tot = 0;
  for (int t0 = 0; t0 < N1; t0 += TILE1) {
    for (int i = t; i < TILE1; i += 256) {
      int p = t0 + i;
      tile[i] = make_float4(xb[p * 3], xb[p * 3 + 1], xb[p * 3 + 2], nb[p]);
    }
    __syncthreads();
    for (int j = 0; j < TILE1; j += 256) {
      float4 p0 = tile[j + lane];
      float4 p1 = tile[j + 64 + lane];
      float4 p2 = tile[j + 128 + lane];
      float4 p3 = tile[j + 192 + lane];
      bool in0 = !(sqr_np(ca, p0.w, dot3_np(cx, cy, cz, p0.x, p0.y, p0.z)) > r2);
      bool in1 = !(sqr_np(ca, p1.w, dot3_np(cx, cy, cz, p1.x, p1.y, p1.z)) > r2);
      bool in2 = !(sqr_np(ca, p2.w, dot3_np(cx, cy, cz, p2.x, p2.y, p2.z)) > r2);
      bool in3 = !(sqr_np(ca, p3.w, dot3_np(cx, cy, cz, p3.x, p3.y, p3.z)) > r2);
      unsigned long long any = __ballot(in0 | in1 | in2 | in3);
      if (any) {  // rare slow path: append in ascending index order (q major, lane minor)
#define SA1_APPEND(inq, pq)                                                     \
        {                                                                       \
          unsigned long long m = __ballot(inq);                                 \
          if (m) {                                                              \
            int rank = __popcll(m & ((1ull << lane) - 1ull));                   \
            int slot = tot + rank;                                              \
            if (inq && slot < NS1) {                                            \
              blx[w * NS1 + slot] = pq.x - cx;                                  \
              bly[w * NS1 + slot] = pq.y - cy;                                  \
              blz[w * NS1 + slot] = pq.z - cz;                                  \
            }                                                                   \
            tot += (int)__popcll(m);                                            \
            if (tot > NS1) tot = NS1;                                           \
          }                                                                     \
        }
        SA1_APPEND(in0, p0)
        SA1_APPEND(in1, p1)
        SA1_APPEND(in2, p2)
        SA1_APPEND(in3, p3)
#undef SA1_APPEND
      }
    }
    __syncthreads();
  }
  // MLP over unique in-ball samples (duplicate padding is idempotent under max)
  int cnt = tot > 0 ? tot : 1;  // centroid is always in its own ball
  float m0 = -FLT_MAX, m1 = -FLT_MAX;
  for (int k = 0; k < cnt; ++k) {
    float fx = blx[w * NS1 + k], fy = bly[w * NS1 + k], fz = blz[w * NS1 + k];
    float h1 = bias1[lane] + w1T[lane] * fx + w1T[64 + lane] * fy + w1T[128 + lane] * fz;
    h1 = fmaxf(h1, 0.0f);
    float a = bias2[lane];
#pragma unroll 8
    for (int c = 0; c < 64; ++c) a += w2T[c * 64 + lane] * __shfl(h1, c);
    a = fmaxf(a, 0.0f);
    float a0 = bias3[lane], a1 = bias3[64 + lane];
#pragma unroll 8
    for (int c = 0; c < 64; ++c) {
      float hv = __shfl(a, c);
      a0 += w3T[c * 128 + lane] * hv;
      a1 += w3T[c * 128 + 64 + lane] * hv;
    }
    a0 = fmaxf(a0, 0.0f); a1 = fmaxf(a1, 0.0f);
    m0 = fmaxf(m0, a0); m1 = fmaxf(m1, a1);
  }
  float* op = l1_pts + ((size_t)b * NP1 + s) * 128;
  op[lane] = m0;
  op[64 + lane] = m1;
  if (lane == 0) {
    float* xp = l1_xyz + ((size_t)b * NP1 + s) * 3;
    xp[0] = cx; xp[1] = cy; xp[2] = cz;
    norms2[b * NP1 + s] = ca;
  }
}

// ---------- SA2 fused: ball query (first-64) + MLP(131->128->256->256) + max ----------
// 512 blocks x 256 threads; wave w -> centroid s = (blockIdx&31)*4 + w of batch blockIdx>>5
__global__ __launch_bounds__(256) void sa2_kernel(
    const float* __restrict__ l1_xyz, const float* __restrict__ norms2,
    const float* __restrict__ l1_pts, const int* __restrict__ fps2_idx,
    const float* __restrict__ w1T, const float* __restrict__ bias1,
    const float* __restrict__ w2T, const float* __restrict__ bias2,
    const float* __restrict__ w3T, const float* __restrict__ bias3,
    float* __restrict__ out) {
  __shared__ float sx[N2], sy[N2], sz[N2], sn[N2];
  __shared__ float blx[4 * NS2], bly[4 * NS2], blz[4 * NS2];
  __shared__ int bli[4 * NS2];
  int b = blockIdx.x >> 5;
  int t = threadIdx.x;
  int w = t >> 6, lane = t & 63;
  int s = ((blockIdx.x & 31) << 2) + w;
  const float* xb = l1_xyz + (size_t)b * N2 * 3;
  const float* nb = norms2 + (size_t)b * N2;
  for (int i = t; i < N2; i += 256) {
    sx[i] = xb[i * 3]; sy[i] = xb[i * 3 + 1]; sz[i] = xb[i * 3 + 2]; sn[i] = nb[i];
  }
  __syncthreads();
  int cidx = fps2_idx[b * NP2 + s];
  float cx = sx[cidx], cy = sy[cidx], cz = sz[cidx], ca = sn[cidx];
  const float r2 = (float)(0.08 * 0.08);
  int tot = 0;
  for (int j = 0; j < N2; j += 64) {
    int i = j + lane;
    float px = sx[i], py = sy[i], pz = sz[i], sb = sn[i];
    bool in = !(sqr_np(ca, sb, dot3_np(cx, cy, cz, px, py, pz)) > r2);
    unsigned long long m = __ballot(in);
    int rank = __popcll(m & ((1ull << lane) - 1ull));
    int slot = tot + rank;
    if (in && slot < NS2) {
      blx[w * NS2 + slot] = px - cx;
      bly[w * NS2 + slot] = py - cy;
      blz[w * NS2 + slot] = pz - cz;
      bli[w * NS2 + slot] = i;
    }
    tot += (int)__popcll(m);
    if (tot > NS2) tot = NS2;
  }
  __syncthreads();
  int cnt = tot > 0 ? tot : 1;
  float mx0 = -FLT_MAX, mx1 = -FLT_MAX, mx2 = -FLT_MAX, mx3 = -FLT_MAX;
  for (int k = 0; k < cnt; ++k) {
    float fx = blx[w * NS2 + k], fy = bly[w * NS2 + k], fz = blz[w * NS2 + k];
    int pidx = bli[w * NS2 + k];
    const float* fp = l1_pts + ((size_t)b * N2 + pidx) * 128;
    float a0 = bias1[lane] + w1T[lane] * fx + w1T[128 + lane] * fy + w1T[256 + lane] * fz;
    float a1 = bias1[64 + lane] + w1T[64 + lane] * fx + w1T[192 + lane] * fy + w1T[320 + lane] * fz;
#pragma unroll 4
    for (int c = 0; c < 128; ++c) {
      float fv = fp[c];
      a0 += w1T[(size_t)(3 + c) * 128 + lane] * fv;
      a1 += w1T[(size_t)(3 + c) * 128 + 64 + lane] * fv;
    }
    float h1a = fmaxf(a0, 0.0f), h1b = fmaxf(a1, 0.0f);
    float acc0 = bias2[lane], acc1 = bias2[64 + lane], acc2 = bias2[128 + lane], acc3 = bias2[192 + lane];
#pragma unroll 4
    for (int c = 0; c < 64; ++c) {
      float hv = __shfl(h1a, c);
      acc0 += w2T[(size_t)c * 256 + lane] * hv;
      acc1 += w2T[(size_t)c * 256 + 64 + lane] * hv;
      acc2 += w2T[(size_t)c * 256 + 128 + lane] * hv;
      acc3 += w2T[(size_t)c * 256 + 192 + lane] * hv;
    }
#pragma unroll 4
    for (int c = 0; c < 64; ++c) {
      float hv = __shfl(h1b, c);
      acc0 += w2T[(size_t)(64 + c) * 256 + lane] * hv;
      acc1 += w2T[(size_t)(64 + c) * 256 + 64 + lane] * hv;
      acc2 += w2T[(size_t)(64 + c) * 256 + 128 + lane] * hv;
      acc3 += w2T[(size_t)(64 + c) * 256 + 192 + lane] * hv;
    }
    float h20 = fmaxf(acc0, 0.0f), h21 = fmaxf(acc1, 0.0f);
    float h22 = fmaxf(acc2, 0.0f), h23 = fmaxf(acc3, 0.0f);
    float o0 = bias3[lane], o1 = bias3[64 + lane], o2 = bias3[128 + lane], o3 = bias3[192 + lane];
#define SA2_L3(hreg, rbase)                                                     \
    {                                                                           \
      _Pragma("unroll 4")                                                       \
      for (int c = 0; c < 64; ++c) {                                            \
        float hv = __shfl(hreg, c);                                             \
        o0 += w3T[(size_t)(rbase + c) * 256 + lane] * hv;                       \
        o1 += w3T[(size_t)(rbase + c) * 256 + 64 + lane] * hv;                  \
        o2 += w3T[(size_t)(rbase + c) * 256 + 128 + lane] * hv;                 \
        o3 += w3T[(size_t)(rbase + c) * 256 + 192 + lane] * hv;                 \
      }                                                                         \
    }
    SA2_L3(h20, 0)
    SA2_L3(h21, 64)
    SA2_L3(h22, 128)
    SA2_L3(h23, 192)
#undef SA2_L3
    mx0 = fmaxf(mx0, fmaxf(o0, 0.0f));
    mx1 = fmaxf(mx1, fmaxf(o1, 0.0f));
    mx2 = fmaxf(mx2, fmaxf(o2, 0.0f));
    mx3 = fmaxf(mx3, fmaxf(o3, 0.0f));
  }
  float* op = out + ((size_t)b * NP2 + s) * 256;
  op[lane] = mx0;
  op[64 + lane] = mx1;
  op[128 + lane] = mx2;
  op[192 + lane] = mx3;
}

extern "C" void kernel_launch(void* const* d_in, const int* in_sizes, int n_in,
                              void* d_out, int out_size, void* d_ws, size_t ws_size,
                              hipStream_t stream) {
  const float* xyz = (const float*)d_in[0];
  const float* sa1_w1 = (const float*)d_in[1];
  const float* sa1_b1 = (const float*)d_in[2];
  const float* sa1_w2 = (const float*)d_in[3];
  const float* sa1_b2 = (const float*)d_in[4];
  const float* sa1_w3 = (const float*)d_in[5];
  const float* sa1_b3 = (const float*)d_in[6];
  const float* sa2_w1 = (const float*)d_in[7];
  const float* sa2_b1 = (const float*)d_in[8];
  const float* sa2_w2 = (const float*)d_in[9];
  const float* sa2_b2 = (const float*)d_in[10];
  const float* sa2_w3 = (const float*)d_in[11];
  const float* sa2_b3 = (const float*)d_in[12];

  if (ws_size < WS_FLOATS * sizeof(float)) return;  // scratch too small: fail loudly

  float* ws = (float*)d_ws;
  float* w1T1 = ws + OFF_W1T1;
  float* w2T1 = ws + OFF_W2T1;
  float* w3T1 = ws + OFF_W3T1;
  float* w1T2 = ws + OFF_W1T2;
  float* w2T2 = ws + OFF_W2T2;
  float* w3T2 = ws + OFF_W3T2;
  float* norms1 = ws + OFF_NORM1;
  float* l1xyz = ws + OFF_L1XYZ;
  float* norms2 = ws + OFF_NORM2;
  float* l1pts = ws + OFF_L1PTS;
  int* fps1i = (int*)(ws + OFF_FPS1I);
  int* fps2i = (int*)(ws + OFF_FPS2I);

  prep_kernel<<<1024, 256, 0, stream>>>(xyz, sa1_w1, sa1_w2, sa1_w3, sa2_w1, sa2_w2, sa2_w3, ws);
  fps1_kernel<<<NB, 512, 0, stream>>>(xyz, fps1i);
  sa1_kernel<<<NB * (NP1 / 4), 256, 0, stream>>>(xyz, norms1, fps1i, w1T1, sa1_b1, w2T1,
                                                 sa1_b2, w3T1, sa1_b3, l1xyz, norms2, l1pts);
  fps2_kernel<<<NB, 64, 0, stream>>>(l1xyz, fps2i);
  sa2_kernel<<<NB * (NP2 / 4), 256, 0, stream>>>(l1xyz, norms2, l1pts, fps2i, w1T2, sa2_b1,
                                                 w2T2, sa2_b2, w3T2, sa2_b3, (float*)d_out);
}